// Round 11
// baseline (129.925 us; speedup 1.0000x reference)
//
#include <hip/hip_runtime.h>

#define NDIM 2048
#define FDIM 64
#define KDIM 8
#define BDIM 32
#define TILE 32     // block tile (32x32); each of 4 waves owns a 16x16 quadrant
#define BFROW 72    // bf16 elems per staging row (64 + 8 pad)
#define FROW2 36    // f32 elems per epilogue-panel row (32 + 4 pad)

typedef __attribute__((ext_vector_type(8))) short short8;
typedef __attribute__((ext_vector_type(4))) float f32x4;

static __device__ __forceinline__ unsigned short f2bf(float x) {
    unsigned u = __float_as_uint(x);                 // RNE to bf16
    return (unsigned short)((u + 0x7fffu + ((u >> 16) & 1u)) >> 16);
}

// ---------------------------------------------------------------------------
// R11: occupancy attack. 32x32 block tile -> acc[8] is ONE f32x4 per k
// (32 VGPR vs 128), LDS 19.4 KB, __launch_bounds__(256,4) -> 4 blocks/CU
// (16 waves/CU, 2x R10) to fill the store queue. Per-element MFMA work
// unchanged. Epilogue is the R8-proven shape: mix -> LDS scatter (<=2-way
// banks) -> row readback -> wide stores (128-B segs per 8 lanes), barriers
// lgkmcnt-only (stores never drained), 4 planes/pass x 8 passes. Stores are
// nontemporal (write-once output). acc consumed ONLY via the proven
// LDS-transpose path (register-reorg epilogues failed in R6/R7/R9).
// ---------------------------------------------------------------------------
__global__ __launch_bounds__(256, 4) void rfm_fused_mfma(
    const float* __restrict__ p, const float* __restrict__ L,
    const float* __restrict__ sr, float* __restrict__ out)
{
    __shared__ float pl[BDIM * KDIM];
    __shared__ __align__(16) char smem[4 * TILE * FROW2 * 4];   // 18432 B

    unsigned short* const An = (unsigned short*)smem;           // [32][72] bf16
    unsigned short* const Am = An + TILE * BFROW;               // [32][72] bf16
    float* const Pp0 = (float*)smem;                            // 4 epilogue panels
    float* const Pp1 = Pp0 + TILE * FROW2;
    float* const Pp2 = Pp1 + TILE * FROW2;
    float* const Pp3 = Pp2 + TILE * FROW2;

    const int n0 = blockIdx.y * TILE;
    const int m0 = blockIdx.x * TILE;
    const int t  = threadIdx.x;
    const int lane = t & 63;
    const int w   = t >> 6;        // wave 0..3
    const int wr  = w >> 1;        // n-side 16-block
    const int wc  = w & 1;         // m-side 16-block
    const int l15 = lane & 15;
    const int l4  = lane >> 4;     // 0..3

    pl[t] = p[t];                  // covered by first __syncthreads below

    f32x4 acc[KDIM];
    #pragma unroll
    for (int k = 0; k < KDIM; ++k) acc[k] = (f32x4){0.f, 0.f, 0.f, 0.f};

    // ---- 1) cov phase (R8 staging pattern, 32 rows) ----
    #pragma unroll
    for (int k = 0; k < KDIM; ++k) {
        const float* Lk = L + (size_t)k * (NDIM * FDIM);

        #pragma unroll
        for (int r = 0; r < 2; ++r) {
            const int idx = t + r * 256;       // 0..511
            const int row = idx >> 4;          // 0..31 (16 float4 per row)
            const int fc  = (idx & 15) << 2;
            const float4 va = *(const float4*)&Lk[(size_t)(n0 + row) * FDIM + fc];
            const float4 vb = *(const float4*)&Lk[(size_t)(m0 + row) * FDIM + fc];
            ushort4 ua, ub;
            ua.x = f2bf(va.x); ua.y = f2bf(va.y); ua.z = f2bf(va.z); ua.w = f2bf(va.w);
            ub.x = f2bf(vb.x); ub.y = f2bf(vb.y); ub.z = f2bf(vb.z); ub.w = f2bf(vb.w);
            *(ushort4*)&An[row * BFROW + fc] = ua;
            *(ushort4*)&Am[row * BFROW + fc] = ub;
        }
        __syncthreads();

        short8 af[2], bv[2];
        #pragma unroll
        for (int s = 0; s < 2; ++s) {
            af[s] = *(const short8*)&An[(wr * 16 + l15) * BFROW + s * 32 + l4 * 8];
            bv[s] = *(const short8*)&Am[(wc * 16 + l15) * BFROW + s * 32 + l4 * 8];
        }
        #pragma unroll
        for (int s = 0; s < 2; ++s)
            acc[k] = __builtin_amdgcn_mfma_f32_16x16x32_bf16(
                af[s], bv[s], acc[k], 0, 0, 0);
        __syncthreads();   // panels consumed; next k (or epilogue) may overwrite
    }

    // Diagonal: C/D map row = l4*4 + reg (n side, from A), col = l15 (m side).
    if (n0 == m0 && wr == wc) {
        #pragma unroll
        for (int k = 0; k < KDIM; ++k)
            #pragma unroll
            for (int reg = 0; reg < 4; ++reg) {
                if (l4 * 4 + reg == l15) {
                    const float q = sr[k * NDIM + n0 + wr * 16 + l15];
                    acc[k][reg] += q * q;
                }
            }
    }

    // ---- 2) epilogue: 4 planes/pass x 8 passes; R8-proven shape ----
    const size_t NN = (size_t)NDIM * NDIM;
    const int rbrow = t >> 3;            // readback row 0..31
    const int rbc4  = (t & 7) * 4;       // readback col 0..28
    const int rl = wr * 16 + l4 * 4;     // scatter row base (+reg)
    const int cl = wc * 16 + l15;        // scatter col
    float* const obase = out + (size_t)(n0 + rbrow) * NDIM + (m0 + rbc4);
    float* const Parr[4] = { Pp0, Pp1, Pp2, Pp3 };

    #pragma unroll 1
    for (int b = 0; b < BDIM; b += 4) {
        // mix + scatter (MFMA layout -> row-major panels)
        #pragma unroll
        for (int u = 0; u < 4; ++u) {
            float pb[KDIM];
            #pragma unroll
            for (int k = 0; k < KDIM; ++k) pb[k] = pl[(b + u) * KDIM + k];
            float* const Pu = Parr[u];
            #pragma unroll
            for (int reg = 0; reg < 4; ++reg) {
                float v = 0.0f;
                #pragma unroll
                for (int k = 0; k < KDIM; ++k) v += pb[k] * acc[k][reg];
                Pu[(rl + reg) * FROW2 + cl] = v;
            }
        }
        asm volatile("s_waitcnt lgkmcnt(0)" ::: "memory");  // my ds_writes done
        __builtin_amdgcn_s_barrier();                        // all writes done
        __builtin_amdgcn_sched_barrier(0);

        // readback rows + nontemporal wide stores; stores stay in flight
        #pragma unroll
        for (int u = 0; u < 4; ++u) {
            const f32x4 wv = *(const f32x4*)&Parr[u][rbrow * FROW2 + rbc4];
            __builtin_nontemporal_store(wv,
                (f32x4*)(obase + (size_t)(b + u) * NN));
        }
        asm volatile("s_waitcnt lgkmcnt(0)" ::: "memory");  // my ds_reads done
        __builtin_amdgcn_s_barrier();                        // safe to overwrite
        __builtin_amdgcn_sched_barrier(0);
    }
}

extern "C" void kernel_launch(void* const* d_in, const int* in_sizes, int n_in,
                              void* d_out, int out_size, void* d_ws, size_t ws_size,
                              hipStream_t stream)
{
    const float* p  = (const float*)d_in[0];   // (B,K) = (32,8)
    const float* L  = (const float*)d_in[1];   // (K,N,F) = (8,2048,64)
    const float* sr = (const float*)d_in[2];   // (K,N)   = (8,2048)
    float* out = (float*)d_out;                // (B,N,N) = (32,2048,2048)

    dim3 grid(NDIM / TILE, NDIM / TILE);       // 64 x 64 = 4096 blocks
    hipLaunchKernelGGL(rfm_fused_mfma, grid, dim3(256), 0, stream,
                       p, L, sr, out);
}